// Round 1
// baseline (570.044 us; speedup 1.0000x reference)
//
#include <hip/hip_runtime.h>

#define M_ACT 4000
#define N_NODE 20000
#define NE 150000
#define DD 128

#define XSTR 392   // edge concat LDS row stride (shorts): 196 words %32 = 4 -> 2-way (free)
#define ASTR 136   // actor LDS row stride (shorts)
#define WSTR 72    // weight chunk row stride (shorts): 36 words %32 = 4 -> 2-way (free)

typedef __attribute__((ext_vector_type(8))) short bh8;
typedef __attribute__((ext_vector_type(4))) float vf4;

#define MFMA16(a, b, c) __builtin_amdgcn_mfma_f32_16x16x32_bf16((a), (b), (c), 0, 0, 0)

__device__ __forceinline__ unsigned short f2bf(float f) {
    unsigned u = __float_as_uint(f);
    u = (u + 0x7fffu + ((u >> 16) & 1u)) >> 16;
    return (unsigned short)u;
}
__device__ __forceinline__ float bf2f(unsigned short s) {
    return __uint_as_float(((unsigned)s) << 16);
}

// ---- GroupNorm(1 group) stats from MFMA C-layout accumulators (wave owns 16 rows x 128 cols)
__device__ __forceinline__ void gn_stats(const vf4* acc, float* mean, float* rs) {
    float s[4], q[4];
#pragma unroll
    for (int i = 0; i < 4; i++) {
        float a = 0.f, b = 0.f;
#pragma unroll
        for (int t = 0; t < 8; t++) { float v = acc[t][i]; a += v; b += v * v; }
        s[i] = a; q[i] = b;
    }
#pragma unroll
    for (int m = 1; m < 16; m <<= 1) {
#pragma unroll
        for (int i = 0; i < 4; i++) {
            s[i] += __shfl_xor(s[i], m, 64);
            q[i] += __shfl_xor(q[i], m, 64);
        }
    }
#pragma unroll
    for (int i = 0; i < 4; i++) {
        float mu = s[i] * (1.0f / 128.0f);
        float var = q[i] * (1.0f / 128.0f) - mu * mu;
        mean[i] = mu;
        rs[i] = rsqrtf(var + 1e-5f);
    }
}

template <bool RELU>
__device__ __forceinline__ void gn_to_lds(const vf4* acc, const float* __restrict__ gw,
                                          const float* __restrict__ gb, unsigned short* sm,
                                          int stride, int cb, int r0, int grp, int lm) {
    float mean[4], rs[4];
    gn_stats(acc, mean, rs);
#pragma unroll
    for (int t = 0; t < 8; t++) {
        int c = 16 * t + lm;
        float w = gw[c], b = gb[c];
#pragma unroll
        for (int i = 0; i < 4; i++) {
            float y = (acc[t][i] - mean[i]) * rs[i] * w + b;
            if (RELU) y = fmaxf(y, 0.0f);
            sm[(r0 + grp * 4 + i) * stride + cb + c] = f2bf(y);
        }
    }
}

__device__ __forceinline__ void load_chunk(const unsigned short* __restrict__ src,
                                           unsigned short* dst, int tid) {
    // 9216 shorts = 1152 x 16B
    for (int idx = tid; idx < 1152; idx += 256) {
        *(uint4*)&dst[idx * 8] = *(const uint4*)&src[idx * 8];
    }
}

// =====================  EDGE KERNEL  =====================
__global__ __launch_bounds__(256, 2) void edge_kernel(
    const float* __restrict__ agts, const float* __restrict__ nodes,
    const float* __restrict__ actor_ctrs, const float* __restrict__ node_ctrs,
    const int* __restrict__ hi, const int* __restrict__ wi,
    const float* __restrict__ Wd1, const float* __restrict__ bd1,
    const float* __restrict__ gnd2_w, const float* __restrict__ gnd2_b,
    const float* __restrict__ gnq_w, const float* __restrict__ gnq_b,
    const float* __restrict__ gnc1_w, const float* __restrict__ gnc1_b,
    const unsigned short* __restrict__ wblob,  // this layer's 16 chunks
    unsigned short* __restrict__ cf2) {
    __shared__ unsigned short smX[64 * XSTR];  // concat [d | q | nodes] bf16
    __shared__ unsigned short smW[128 * WSTR];
    __shared__ int smHi[64];
    __shared__ int smWi[64];
    __shared__ float smCtr[64 * 2];

    const int tid = threadIdx.x;
    const int wave = tid >> 6, lane = tid & 63, grp = lane >> 4, lm = lane & 15;
    const int e0 = blockIdx.x * 64;
    const int r0 = wave * 16;
    const int arow = r0 + lm;  // this lane's A row within block

    // phase 0: indices + ctr diffs
    if (tid < 64) {
        int e = e0 + tid;
        int h = 0, w = 0;
        if (e < NE) { h = hi[e]; w = wi[e]; }
        smHi[tid] = h;
        smWi[tid] = w;
        smCtr[tid * 2 + 0] = actor_ctrs[h * 2 + 0] - node_ctrs[w * 2 + 0];
        smCtr[tid * 2 + 1] = actor_ctrs[h * 2 + 1] - node_ctrs[w * 2 + 1];
    }
    __syncthreads();
    // nodes gather -> smX cols 256..383 (bf16)
    for (int idx = tid; idx < 64 * 32; idx += 256) {
        int r = idx >> 5, q = idx & 31;
        const float4 v = *(const float4*)(nodes + (size_t)smWi[r] * DD + q * 4);
        unsigned lo = (unsigned)f2bf(v.x) | ((unsigned)f2bf(v.y) << 16);
        unsigned hi2 = (unsigned)f2bf(v.z) | ((unsigned)f2bf(v.w) << 16);
        *(uint2*)&smX[r * XSTR + 256 + q * 4] = make_uint2(lo, hi2);
    }
    __syncthreads();

    vf4 acc[8];

    // ---- G1: d = relu(gn(d0 @ Wd2^T)); d0 built analytically from ctr_d
    {
        const float cx = smCtr[arow * 2 + 0], cy = smCtr[arow * 2 + 1];
#pragma unroll
        for (int t = 0; t < 8; t++) acc[t] = (vf4){0.f, 0.f, 0.f, 0.f};
        for (int ch = 0; ch < 2; ch++) {
            load_chunk(wblob + (0 + ch) * 9216, smW, tid);
            __syncthreads();
#pragma unroll
            for (int k0 = 0; k0 < 64; k0 += 32) {
                int kb = ch * 64 + k0 + grp * 8;
                bh8 a;
#pragma unroll
                for (int j = 0; j < 8; j++) {
                    int c = kb + j;
                    float v = fmaf(cy, Wd1[c * 2 + 1], fmaf(cx, Wd1[c * 2 + 0], bd1[c]));
                    a[j] = (short)f2bf(fmaxf(v, 0.f));
                }
#pragma unroll
                for (int t = 0; t < 8; t++) {
                    bh8 b = *(const bh8*)&smW[(16 * t + lm) * WSTR + k0 + grp * 8];
                    acc[t] = MFMA16(a, b, acc[t]);
                }
            }
            __syncthreads();
        }
        gn_to_lds<true>(acc, gnd2_w, gnd2_b, smX, XSTR, 0, r0, grp, lm);
    }

    // ---- G2: q = relu(gn(agts[hi] @ Wq^T)); A-frag direct from global (L2-resident)
    {
        const float* ap = agts + (size_t)smHi[arow] * DD;
#pragma unroll
        for (int t = 0; t < 8; t++) acc[t] = (vf4){0.f, 0.f, 0.f, 0.f};
        for (int ch = 0; ch < 2; ch++) {
            load_chunk(wblob + (2 + ch) * 9216, smW, tid);
            __syncthreads();
#pragma unroll
            for (int k0 = 0; k0 < 64; k0 += 32) {
                int kb = ch * 64 + k0 + grp * 8;
                float4 v0 = *(const float4*)(ap + kb);
                float4 v1 = *(const float4*)(ap + kb + 4);
                bh8 a;
                a[0] = (short)f2bf(v0.x); a[1] = (short)f2bf(v0.y);
                a[2] = (short)f2bf(v0.z); a[3] = (short)f2bf(v0.w);
                a[4] = (short)f2bf(v1.x); a[5] = (short)f2bf(v1.y);
                a[6] = (short)f2bf(v1.z); a[7] = (short)f2bf(v1.w);
#pragma unroll
                for (int t = 0; t < 8; t++) {
                    bh8 b = *(const bh8*)&smW[(16 * t + lm) * WSTR + k0 + grp * 8];
                    acc[t] = MFMA16(a, b, acc[t]);
                }
            }
            __syncthreads();
        }
        gn_to_lds<true>(acc, gnq_w, gnq_b, smX, XSTR, 128, r0, grp, lm);
    }

    // ---- G3: cf1 = relu(gn(concat @ Wc1^T)), K=384
    {
#pragma unroll
        for (int t = 0; t < 8; t++) acc[t] = (vf4){0.f, 0.f, 0.f, 0.f};
        for (int ch = 0; ch < 6; ch++) {
            load_chunk(wblob + (4 + ch) * 9216, smW, tid);
            __syncthreads();
#pragma unroll
            for (int k0 = 0; k0 < 64; k0 += 32) {
                bh8 a = *(const bh8*)&smX[arow * XSTR + ch * 64 + k0 + grp * 8];
#pragma unroll
                for (int t = 0; t < 8; t++) {
                    bh8 b = *(const bh8*)&smW[(16 * t + lm) * WSTR + k0 + grp * 8];
                    acc[t] = MFMA16(a, b, acc[t]);
                }
            }
            __syncthreads();
        }
        gn_to_lds<true>(acc, gnc1_w, gnc1_b, smX, XSTR, 0, r0, grp, lm);  // cf1 over d region
    }

    // ---- G4: cf2 = cf1 @ Wc2^T  (no gn) -> global bf16
    {
#pragma unroll
        for (int t = 0; t < 8; t++) acc[t] = (vf4){0.f, 0.f, 0.f, 0.f};
        for (int ch = 0; ch < 2; ch++) {
            load_chunk(wblob + (10 + ch) * 9216, smW, tid);
            __syncthreads();
#pragma unroll
            for (int k0 = 0; k0 < 64; k0 += 32) {
                bh8 a = *(const bh8*)&smX[arow * XSTR + ch * 64 + k0 + grp * 8];
#pragma unroll
                for (int t = 0; t < 8; t++) {
                    bh8 b = *(const bh8*)&smW[(16 * t + lm) * WSTR + k0 + grp * 8];
                    acc[t] = MFMA16(a, b, acc[t]);
                }
            }
            __syncthreads();
        }
#pragma unroll
        for (int i = 0; i < 4; i++) {
            int e = e0 + r0 + grp * 4 + i;
            if (e < NE) {
                unsigned short* dst = cf2 + (size_t)e * DD;
#pragma unroll
                for (int t = 0; t < 8; t++) dst[16 * t + lm] = f2bf(acc[t][i]);
            }
        }
    }
}

// =====================  SEGMENTED SUM (wave per actor)  =====================
__global__ __launch_bounds__(256) void ssum_kernel(const unsigned short* __restrict__ cf2,
                                                   const int* __restrict__ offs,
                                                   const int* __restrict__ perm,
                                                   float* __restrict__ ssum) {
    int wid = (blockIdx.x * 256 + threadIdx.x) >> 6;
    int lane = threadIdx.x & 63;
    if (wid >= M_ACT) return;
    float s0 = 0.f, s1 = 0.f;
    int j1 = offs[wid + 1];
    for (int j = offs[wid]; j < j1; j++) {
        int e = perm[j];
        unsigned u = *(const unsigned*)&cf2[(size_t)e * DD + lane * 2];
        s0 += bf2f((unsigned short)(u & 0xffffu));
        s1 += bf2f((unsigned short)(u >> 16));
    }
    *(float2*)&ssum[(size_t)wid * DD + lane * 2] = make_float2(s0, s1);
}

// =====================  ACTOR KERNEL  =====================
__global__ __launch_bounds__(256, 2) void actor_kernel(
    const float* __restrict__ agts, const float* __restrict__ ssum,
    const float* __restrict__ gnn_w, const float* __restrict__ gnn_b,
    const float* __restrict__ gnl_w, const float* __restrict__ gnl_b,
    const unsigned short* __restrict__ wblob,  // layer base
    float* __restrict__ dst) {
    __shared__ unsigned short smA[64 * ASTR];
    __shared__ unsigned short smW[128 * WSTR];
    const int tid = threadIdx.x;
    const int wave = tid >> 6, lane = tid & 63, grp = lane >> 4, lm = lane & 15;
    const int m0 = blockIdx.x * 64;
    const int r0 = wave * 16;
    const int arow = r0 + lm;

    for (int idx = tid; idx < 64 * 32; idx += 256) {
        int r = idx >> 5, q = idx & 31;
        int m = m0 + r;
        if (m >= M_ACT) m = 0;
        const float4 v = *(const float4*)(agts + (size_t)m * DD + q * 4);
        unsigned lo = (unsigned)f2bf(v.x) | ((unsigned)f2bf(v.y) << 16);
        unsigned hi2 = (unsigned)f2bf(v.z) | ((unsigned)f2bf(v.w) << 16);
        *(uint2*)&smA[r * ASTR + q * 4] = make_uint2(lo, hi2);
    }
    __syncthreads();

    vf4 acc[8];
    // Ga: agts @ Wa^T  (chunks 12,13)
#pragma unroll
    for (int t = 0; t < 8; t++) acc[t] = (vf4){0.f, 0.f, 0.f, 0.f};
    for (int ch = 0; ch < 2; ch++) {
        load_chunk(wblob + (12 + ch) * 9216, smW, tid);
        __syncthreads();
#pragma unroll
        for (int k0 = 0; k0 < 64; k0 += 32) {
            bh8 a = *(const bh8*)&smA[arow * ASTR + ch * 64 + k0 + grp * 8];
#pragma unroll
            for (int t = 0; t < 8; t++) {
                bh8 b = *(const bh8*)&smW[(16 * t + lm) * WSTR + k0 + grp * 8];
                acc[t] = MFMA16(a, b, acc[t]);
            }
        }
        __syncthreads();
    }
    // += scatter sums, then gn+relu back into smA (wave owns its rows)
#pragma unroll
    for (int t = 0; t < 8; t++) {
#pragma unroll
        for (int i = 0; i < 4; i++) {
            int m = m0 + r0 + grp * 4 + i;
            if (m < M_ACT) acc[t][i] += ssum[(size_t)m * DD + 16 * t + lm];
        }
    }
    gn_to_lds<true>(acc, gnn_w, gnn_b, smA, ASTR, 0, r0, grp, lm);

    // Gl: x @ Wl^T (chunks 14,15)
#pragma unroll
    for (int t = 0; t < 8; t++) acc[t] = (vf4){0.f, 0.f, 0.f, 0.f};
    for (int ch = 0; ch < 2; ch++) {
        load_chunk(wblob + (14 + ch) * 9216, smW, tid);
        __syncthreads();
#pragma unroll
        for (int k0 = 0; k0 < 64; k0 += 32) {
            bh8 a = *(const bh8*)&smA[arow * ASTR + ch * 64 + k0 + grp * 8];
#pragma unroll
            for (int t = 0; t < 8; t++) {
                bh8 b = *(const bh8*)&smW[(16 * t + lm) * WSTR + k0 + grp * 8];
                acc[t] = MFMA16(a, b, acc[t]);
            }
        }
        __syncthreads();
    }
    // gn (no relu) + residual + relu -> dst
    {
        float mean[4], rs[4];
        gn_stats(acc, mean, rs);
#pragma unroll
        for (int t = 0; t < 8; t++) {
            int c = 16 * t + lm;
            float w = gnl_w[c], b = gnl_b[c];
#pragma unroll
            for (int i = 0; i < 4; i++) {
                int m = m0 + r0 + grp * 4 + i;
                if (m < M_ACT) {
                    float y = (acc[t][i] - mean[i]) * rs[i] * w + b;
                    y += agts[(size_t)m * DD + c];
                    dst[(size_t)m * DD + c] = fmaxf(y, 0.f);
                }
            }
        }
    }
}

// =====================  SETUP KERNELS  =====================
__global__ void hist_kernel(const int* __restrict__ hi, int* __restrict__ hist) {
    int e = blockIdx.x * 256 + threadIdx.x;
    if (e < NE) atomicAdd(&hist[hi[e]], 1);
}

__global__ void scan_kernel(const int* __restrict__ hist, int* __restrict__ offs,
                            int* __restrict__ cursor) {
    __shared__ int part[256];
    int t = threadIdx.x;
    int base = t * 16;
    int s = 0;
    if (base < M_ACT)
        for (int i = 0; i < 16; i++) s += hist[base + i];
    part[t] = s;
    __syncthreads();
    for (int d = 1; d < 256; d <<= 1) {
        int u = (t >= d) ? part[t - d] : 0;
        __syncthreads();
        part[t] += u;
        __syncthreads();
    }
    int excl = part[t] - s;
    if (base < M_ACT) {
        int run = excl;
        for (int i = 0; i < 16; i++) {
            offs[base + i] = run;
            cursor[base + i] = run;
            run += hist[base + i];
        }
        if (base + 16 == M_ACT) offs[M_ACT] = run;
    }
}

__global__ void scatter_kernel(const int* __restrict__ hi, int* __restrict__ cursor,
                               int* __restrict__ perm) {
    int e = blockIdx.x * 256 + threadIdx.x;
    if (e < NE) {
        int p = atomicAdd(&cursor[hi[e]], 1);
        perm[p] = e;
    }
}

__global__ void convert_kernel(const float* __restrict__ Wd2, const float* __restrict__ Wq,
                               const float* __restrict__ Wc1, const float* __restrict__ Wc2,
                               const float* __restrict__ Wa, const float* __restrict__ Wl,
                               unsigned short* __restrict__ wblob) {
    int ci = blockIdx.x;  // 0..31
    int l = ci >> 4, r = ci & 15;
    const float* src;
    int kc, K;
    if (r < 2)       { src = Wd2 + l * 16384; kc = r;      K = 128; }
    else if (r < 4)  { src = Wq  + l * 16384; kc = r - 2;  K = 128; }
    else if (r < 10) { src = Wc1 + l * 49152; kc = r - 4;  K = 384; }
    else if (r < 12) { src = Wc2 + l * 16384; kc = r - 10; K = 128; }
    else if (r < 14) { src = Wa  + l * 16384; kc = r - 12; K = 128; }
    else             { src = Wl  + l * 16384; kc = r - 14; K = 128; }
    unsigned short* dst = wblob + (size_t)ci * 9216;
    for (int idx = threadIdx.x; idx < 9216; idx += 256) {
        int n = idx / 72, kk = idx - n * 72;
        float v = (kk < 64) ? src[n * K + kc * 64 + kk] : 0.f;
        dst[idx] = f2bf(v);
    }
}

extern "C" void kernel_launch(void* const* d_in, const int* in_sizes, int n_in,
                              void* d_out, int out_size, void* d_ws, size_t ws_size,
                              hipStream_t stream) {
    const float* actors = (const float*)d_in[0];
    const float* nodes = (const float*)d_in[1];
    const float* actor_ctrs = (const float*)d_in[2];
    const float* node_ctrs = (const float*)d_in[3];
    const int* hi = (const int*)d_in[4];
    const int* wi = (const int*)d_in[5];
    const float* Wd1 = (const float*)d_in[6];
    const float* bd1 = (const float*)d_in[7];
    const float* Wd2 = (const float*)d_in[8];
    const float* gnd2_w = (const float*)d_in[9];
    const float* gnd2_b = (const float*)d_in[10];
    const float* Wq = (const float*)d_in[11];
    const float* gnq_w = (const float*)d_in[12];
    const float* gnq_b = (const float*)d_in[13];
    const float* Wc1 = (const float*)d_in[14];
    const float* gnc1_w = (const float*)d_in[15];
    const float* gnc1_b = (const float*)d_in[16];
    const float* Wc2 = (const float*)d_in[17];
    const float* Wa = (const float*)d_in[18];
    const float* gnn_w = (const float*)d_in[19];
    const float* gnn_b = (const float*)d_in[20];
    const float* Wl = (const float*)d_in[21];
    const float* gnl_w = (const float*)d_in[22];
    const float* gnl_b = (const float*)d_in[23];
    float* out = (float*)d_out;

    char* ws = (char*)d_ws;
    unsigned short* wblob = (unsigned short*)ws;  ws += 2 * 16 * 9216 * 2;       // 589824 B
    unsigned short* cf2 = (unsigned short*)ws;    ws += (size_t)NE * DD * 2;     // 38.4 MB
    float* ssum = (float*)ws;                     ws += (size_t)M_ACT * DD * 4;  // 2.048 MB
    float* A1 = (float*)ws;                       ws += (size_t)M_ACT * DD * 4;  // 2.048 MB
    int* hist = (int*)ws;                         ws += M_ACT * 4;
    int* offs = (int*)ws;                         ws += (M_ACT + 4) * 4;
    int* cursor = (int*)ws;                       ws += M_ACT * 4;
    int* perm = (int*)ws;                         ws += NE * 4;

    hipMemsetAsync(hist, 0, M_ACT * 4, stream);
    hist_kernel<<<(NE + 255) / 256, 256, 0, stream>>>(hi, hist);
    scan_kernel<<<1, 256, 0, stream>>>(hist, offs, cursor);
    scatter_kernel<<<(NE + 255) / 256, 256, 0, stream>>>(hi, cursor, perm);
    convert_kernel<<<32, 256, 0, stream>>>(Wd2, Wq, Wc1, Wc2, Wa, Wl, wblob);

    const int EB = (NE + 63) / 64;
    const int AB = (M_ACT + 63) / 64;
    // layer 0
    edge_kernel<<<EB, 256, 0, stream>>>(actors, nodes, actor_ctrs, node_ctrs, hi, wi,
                                        Wd1, bd1, gnd2_w, gnd2_b, gnq_w, gnq_b, gnc1_w, gnc1_b,
                                        wblob, cf2);
    ssum_kernel<<<(M_ACT * 64) / 256, 256, 0, stream>>>(cf2, offs, perm, ssum);
    actor_kernel<<<AB, 256, 0, stream>>>(actors, ssum, gnn_w, gnn_b, gnl_w, gnl_b, wblob, A1);
    // layer 1
    edge_kernel<<<EB, 256, 0, stream>>>(A1, nodes, actor_ctrs, node_ctrs, hi, wi,
                                        Wd1 + 256, bd1 + 128, gnd2_w + 128, gnd2_b + 128,
                                        gnq_w + 128, gnq_b + 128, gnc1_w + 128, gnc1_b + 128,
                                        wblob + 16 * 9216, cf2);
    ssum_kernel<<<(M_ACT * 64) / 256, 256, 0, stream>>>(cf2, offs, perm, ssum);
    actor_kernel<<<AB, 256, 0, stream>>>(A1, ssum, gnn_w + 128, gnn_b + 128, gnl_w + 128,
                                         gnl_b + 128, wblob + 16 * 9216, out);
}